// Round 1
// baseline (470.565 us; speedup 1.0000x reference)
//
#include <hip/hip_runtime.h>

#define OC 64
#define IC 32
#define KC 16
#define DD 16
#define HH 32
#define WW 32
#define NB 2

// ---------------------------------------------------------------------------
// Kernel 1: construct the dense 5x5x5 kernel from W and P (trilinear, gather)
// K[o][c][l][j][i], l=depth (from P[0]), j=height (from P[2]), i=width (P[1])
// One block per (o,c); thread t = cell index (125 cells, 128 threads).
// ---------------------------------------------------------------------------
__global__ __launch_bounds__(128) void build_k(const float* __restrict__ W,
                                               const float* __restrict__ P,
                                               float* __restrict__ Kg) {
    const int pair = blockIdx.x;      // 0..2047
    const int o = pair >> 5;
    const int c = pair & 31;
    const int cell = threadIdx.x;
    if (cell >= 125) return;
    const int l = cell / 25;
    const int j = (cell / 5) % 5;
    const int i = cell % 5;
    const float fl = (float)l, fj = (float)j, fi = (float)i;
    const int base = (o * IC + c) * KC;
    float acc = 0.f;
    #pragma unroll
    for (int k = 0; k < KC; ++k) {
        const float w  = W[base + k];
        const float p1 = P[0 * OC * IC * KC + base + k] + 2.0f;  // depth
        const float p2 = P[1 * OC * IC * KC + base + k] + 2.0f;  // width
        const float p3 = P[2 * OC * IC * KC + base + k] + 2.0f;  // height
        const float f1 = floorf(p1), r1 = p1 - f1;
        const float f2 = floorf(p2), r2 = p2 - f2;
        const float f3 = floorf(p3), r3 = p3 - f3;
        const float wl = (fl == f1) ? (1.f - r1) : ((fl == f1 + 1.f) ? r1 : 0.f);
        const float wj = (fj == f3) ? (1.f - r3) : ((fj == f3 + 1.f) ? r3 : 0.f);
        const float wi = (fi == f2) ? (1.f - r2) : ((fi == f2 + 1.f) ? r2 : 0.f);
        acc += w * (wl * wj * wi);
    }
    Kg[(o * IC + c) * 125 + cell] = acc;
}

// ---------------------------------------------------------------------------
// Kernel 2: dense 3D conv, pad=2, stride=1.
// Block = 256 threads = 4 waves. Block owns (n, o, dbase..dbase+3).
// Wave wd handles d = dbase + wd. Lane computes a 4x4 (h,w) output tile.
// x staged per channel: 8 padded planes [8][36][38] in LDS (stride 38 for
// 2-way-free bank access on float2 reads).
// K row (o,c) loaded with block-uniform addresses -> SGPRs.
// ---------------------------------------------------------------------------
#define XROW 38
#define XPLANE (36 * XROW)   // 1368

__global__ __launch_bounds__(256) void conv3d(const float* __restrict__ x,
                                              const float* __restrict__ Kg,
                                              const float* __restrict__ bias,
                                              float* __restrict__ out) {
    const int bx = blockIdx.x;          // 0..511
    const int db = bx & 3;
    const int o  = (bx >> 2) & 63;
    const int n  = bx >> 8;
    const int dbase = db * 4;

    __shared__ float sX[8 * XPLANE];    // 43776 B

    const int tid  = threadIdx.x;
    const int wd   = tid >> 6;          // wave id = local d slice
    const int lane = tid & 63;
    const int h0 = (lane >> 3) * 4;
    const int w0 = (lane & 7) * 4;

    float acc[4][4] = {};
    const float* Ko = Kg + o * (IC * 125);

    for (int c = 0; c < IC; ++c) {
        __syncthreads();
        // ---- stage 8 padded planes of channel c ----
        const float* xc = x + (size_t)((n * IC + c) * DD) * (HH * WW);
        for (int idx = tid; idx < 8 * 36 * 36; idx += 256) {
            const int l8  = idx / 1296;
            const int rem = idx - l8 * 1296;
            const int hh  = rem / 36;
            const int ww  = rem - hh * 36;
            const int zd = dbase - 2 + l8;
            const int hr = hh - 2, wr = ww - 2;
            float v = 0.f;
            if ((unsigned)zd < DD && (unsigned)hr < HH && (unsigned)wr < WW)
                v = xc[zd * (HH * WW) + hr * WW + wr];
            sX[l8 * XPLANE + hh * XROW + ww] = v;
        }
        __syncthreads();

        const float* Kc = Ko + c * 125;
        #pragma unroll
        for (int l = 0; l < 5; ++l) {
            // uniform loads -> SGPRs
            float kv[25];
            #pragma unroll
            for (int t = 0; t < 25; ++t) kv[t] = Kc[l * 25 + t];
            const float* plane = &sX[(wd + l) * XPLANE];
            #pragma unroll
            for (int jr = 0; jr < 8; ++jr) {
                float xv[8];
                const float* row = plane + (h0 + jr) * XROW + w0;
                #pragma unroll
                for (int q = 0; q < 8; q += 2) {
                    const float2 t2 = *reinterpret_cast<const float2*>(row + q);
                    xv[q] = t2.x; xv[q + 1] = t2.y;
                }
                #pragma unroll
                for (int r = 0; r < 4; ++r) {
                    const int j = jr - r;
                    if (j < 0 || j > 4) continue;       // compile-time pruned
                    #pragma unroll
                    for (int i = 0; i < 5; ++i) {
                        const float kw = kv[j * 5 + i];
                        #pragma unroll
                        for (int q = 0; q < 4; ++q)
                            acc[r][q] = fmaf(xv[q + i], kw, acc[r][q]);
                    }
                }
            }
        }
    }

    const float b = bias[o];
    const int d = dbase + wd;
    #pragma unroll
    for (int r = 0; r < 4; ++r) {
        const int h = h0 + r;
        float* op = out + (size_t)(((n * OC + o) * DD + d) * HH + h) * WW + w0;
        float4 v = make_float4(acc[r][0] + b, acc[r][1] + b,
                               acc[r][2] + b, acc[r][3] + b);
        *reinterpret_cast<float4*>(op) = v;
    }
}

extern "C" void kernel_launch(void* const* d_in, const int* in_sizes, int n_in,
                              void* d_out, int out_size, void* d_ws, size_t ws_size,
                              hipStream_t stream) {
    const float* x    = (const float*)d_in[0];
    const float* W    = (const float*)d_in[1];
    const float* P    = (const float*)d_in[2];
    const float* bias = (const float*)d_in[3];
    float* outp = (float*)d_out;
    float* Kg   = (float*)d_ws;   // 64*32*125*4 = 1,024,000 B

    build_k<<<OC * IC, 128, 0, stream>>>(W, P, Kg);
    conv3d<<<NB * OC * 4, 256, 0, stream>>>(x, Kg, bias, outp);
}

// Round 2
// 57.055 us; speedup vs baseline: 8.2475x; 8.2475x over previous
//
#include <hip/hip_runtime.h>

#define OC 64
#define IC 32
#define KC 16

typedef __attribute__((ext_vector_type(8))) short bf16x8;
typedef __attribute__((ext_vector_type(4))) float f32x4;

__device__ inline unsigned short f2bf(float f) {
    unsigned u = __builtin_bit_cast(unsigned, f);
    unsigned r = (u + 0x7fffu + ((u >> 16) & 1u)) >> 16;
    return (unsigned short)r;
}

// ---------------------------------------------------------------------------
// Kernel 1: build trilinear kernel -> bf16 Kb[cell=125][o=64][c=32]
// (same math as round-1 verified version; only output layout/dtype changed)
// ---------------------------------------------------------------------------
__global__ __launch_bounds__(128) void build_k(const float* __restrict__ W,
                                               const float* __restrict__ P,
                                               short* __restrict__ Kb) {
    const int pair = blockIdx.x;      // 0..2047
    const int o = pair >> 5;
    const int c = pair & 31;
    const int cell = threadIdx.x;
    if (cell >= 125) return;
    const int l = cell / 25;
    const int j = (cell / 5) % 5;
    const int i = cell % 5;
    const float fl = (float)l, fj = (float)j, fi = (float)i;
    const int base = (o * IC + c) * KC;
    float acc = 0.f;
    #pragma unroll
    for (int k = 0; k < KC; ++k) {
        const float w  = W[base + k];
        const float p1 = P[0 * OC * IC * KC + base + k] + 2.0f;  // depth
        const float p2 = P[1 * OC * IC * KC + base + k] + 2.0f;  // width
        const float p3 = P[2 * OC * IC * KC + base + k] + 2.0f;  // height
        const float f1 = floorf(p1), r1 = p1 - f1;
        const float f2 = floorf(p2), r2 = p2 - f2;
        const float f3 = floorf(p3), r3 = p3 - f3;
        const float wl = (fl == f1) ? (1.f - r1) : ((fl == f1 + 1.f) ? r1 : 0.f);
        const float wj = (fj == f3) ? (1.f - r3) : ((fj == f3 + 1.f) ? r3 : 0.f);
        const float wi = (fi == f2) ? (1.f - r2) : ((fi == f2 + 1.f) ? r2 : 0.f);
        acc += w * (wl * wj * wi);
    }
    Kb[(cell * OC + o) * IC + c] = (short)f2bf(acc);
}

// ---------------------------------------------------------------------------
// Kernel 2: transpose + zero-pad x -> bf16 x_p[n][z=20][h=36][w=36][slot=4][8c]
// slot s at width w holds channel-group (s ^ (w&3))  (XOR swizzle applied at
// the GLOBAL source so LDS staging is a verbatim copy and reads are
// conflict-free).
// ---------------------------------------------------------------------------
__global__ __launch_bounds__(128) void xpose(const float* __restrict__ x,
                                             short* __restrict__ xp) {
    const int b = blockIdx.x;          // 0..1439 = n(2) x z(20) x h(36)
    const int n = b / 720;
    const int rem = b - n * 720;
    const int z = rem / 36;
    const int h = rem - z * 36;
    const int zr = z - 2, hr = h - 2;
    short* orow = xp + (size_t)((n * 20 + z) * 36 + h) * (36 * 32);

    if ((unsigned)zr >= 16u || (unsigned)hr >= 32u) {
        for (int idx = threadIdx.x; idx < 144; idx += 128)
            *reinterpret_cast<float4*>(orow + idx * 8) = make_float4(0.f, 0.f, 0.f, 0.f);
        return;
    }

    __shared__ float sR[32][36];
    const float* xb = x + ((size_t)(n * 32) * 16 + zr) * 1024 + hr * 32;
    for (int idx = threadIdx.x; idx < 32 * 36; idx += 128) {
        const int c = idx / 36;
        const int w = idx - c * 36;
        const int wr = w - 2;
        float v = 0.f;
        if ((unsigned)wr < 32u) v = xb[(size_t)c * 16384 + wr];
        sR[c][w] = v;
    }
    __syncthreads();
    for (int idx = threadIdx.x; idx < 144; idx += 128) {
        const int w = idx >> 2;
        const int s = idx & 3;
        const int c0 = (s ^ (w & 3)) * 8;
        bf16x8 pk;
        #pragma unroll
        for (int e = 0; e < 8; ++e) pk[e] = (short)f2bf(sR[c0 + e][w]);
        *reinterpret_cast<bf16x8*>(orow + idx * 8) = pk;
    }
}

// ---------------------------------------------------------------------------
// Kernel 3: implicit-GEMM conv via MFMA 16x16x32 bf16.
// Block = (n, d, h0=4 rows), 512 threads = 8 waves (2 o-tiles x 4 h-rows).
// LDS: one 92KB stage of x_p window [z=5][h=8][w=36][c=32] covering ALL taps.
// Per wave per cell: 2 global A-frag loads (Kb, L1/L2-resident),
// 2 ds_read_b128 B-frags (conflict-free via source swizzle), 4 MFMA.
// ---------------------------------------------------------------------------
__global__ __launch_bounds__(512) void conv_mfma(const short* __restrict__ Kb,
                                                 const short* __restrict__ xp,
                                                 const float* __restrict__ bias,
                                                 float* __restrict__ out) {
    const int bx = blockIdx.x;              // 0..255
    const int hb = bx & 7;
    const int d  = (bx >> 3) & 15;
    const int n  = bx >> 7;
    const int h0 = hb * 4;

    __shared__ short sX[5 * 8 * 36 * 32];   // 92160 B

    const int tid = threadIdx.x;

    // ---- stage: 5 z-slices, each a contiguous 18432B window of x_p ----
    {
        const short* src = xp + (size_t)((n * 20 + d) * 36 + h0) * 1152;
        for (int t = tid; t < 5760; t += 512) {
            const int zi = t / 1152;
            const int rm = t - zi * 1152;
            const float4 v = *reinterpret_cast<const float4*>(src + zi * 41472 + rm * 8);
            *reinterpret_cast<float4*>(sX + t * 8) = v;
        }
    }
    __syncthreads();

    const int wv   = tid >> 6;
    const int lane = tid & 63;
    const int mi   = wv & 1;                // o-tile
    const int r    = wv >> 1;               // h-row within block
    const int o_base = mi * 32;
    const int col = lane & 15;
    const int cg  = lane >> 4;              // k-block (8 channels)

    // per-lane A base: Kb[cell][o_base+col + 16*mf][cg*8 ..]
    const short* Abase = Kb + (o_base + col) * 32 + cg * 8;

    f32x4 acc[2][2] = {{{0.f, 0.f, 0.f, 0.f}, {0.f, 0.f, 0.f, 0.f}},
                       {{0.f, 0.f, 0.f, 0.f}, {0.f, 0.f, 0.f, 0.f}}};

    for (int l = 0; l < 5; ++l) {
        #pragma unroll
        for (int j = 0; j < 5; ++j) {
            const short* Brow = sX + (l * 8 + r + j) * (36 * 32);
            #pragma unroll
            for (int i = 0; i < 5; ++i) {
                const int cell = (l * 5 + j) * 5 + i;
                const short* Ac = Abase + cell * 2048;
                const bf16x8 a0 = *reinterpret_cast<const bf16x8*>(Ac);
                const bf16x8 a1 = *reinterpret_cast<const bf16x8*>(Ac + 512);
                const int w0x = col + i;
                const int w1x = col + 16 + i;
                const bf16x8 b0 = *reinterpret_cast<const bf16x8*>(
                    Brow + w0x * 32 + ((cg ^ (w0x & 3)) << 3));
                const bf16x8 b1 = *reinterpret_cast<const bf16x8*>(
                    Brow + w1x * 32 + ((cg ^ (w1x & 3)) << 3));
                acc[0][0] = __builtin_amdgcn_mfma_f32_16x16x32_bf16(a0, b0, acc[0][0], 0, 0, 0);
                acc[0][1] = __builtin_amdgcn_mfma_f32_16x16x32_bf16(a0, b1, acc[0][1], 0, 0, 0);
                acc[1][0] = __builtin_amdgcn_mfma_f32_16x16x32_bf16(a1, b0, acc[1][0], 0, 0, 0);
                acc[1][1] = __builtin_amdgcn_mfma_f32_16x16x32_bf16(a1, b1, acc[1][1], 0, 0, 0);
            }
        }
    }

    // ---- epilogue: C/D layout col=lane&15 (w), row=cg*4+reg (o) ----
    const int h = h0 + r;
    #pragma unroll
    for (int mf = 0; mf < 2; ++mf) {
        #pragma unroll
        for (int f = 0; f < 2; ++f) {
            #pragma unroll
            for (int reg = 0; reg < 4; ++reg) {
                const int o = o_base + mf * 16 + cg * 4 + reg;
                const int w = f * 16 + col;
                out[(((size_t)(n * 64 + o) * 16 + d) * 32 + h) * 32 + w] =
                    acc[mf][f][reg] + bias[o];
            }
        }
    }
}

extern "C" void kernel_launch(void* const* d_in, const int* in_sizes, int n_in,
                              void* d_out, int out_size, void* d_ws, size_t ws_size,
                              hipStream_t stream) {
    const float* x    = (const float*)d_in[0];
    const float* W    = (const float*)d_in[1];
    const float* P    = (const float*)d_in[2];
    const float* bias = (const float*)d_in[3];
    float* outp = (float*)d_out;

    short* Kb = (short*)d_ws;                          // 125*64*32*2 = 512000 B
    short* xp = (short*)((char*)d_ws + 524288);        // 2*20*36*36*64 = 3317760 B

    build_k<<<OC * IC, 128, 0, stream>>>(W, P, Kb);
    xpose<<<2 * 20 * 36, 128, 0, stream>>>(x, xp);
    conv_mfma<<<256, 512, 0, stream>>>(Kb, xp, bias, outp);
}

// Round 3
// 46.838 us; speedup vs baseline: 10.0466x; 1.2181x over previous
//
#include <hip/hip_runtime.h>

#define OC 64
#define IC 32
#define KC 16

typedef __attribute__((ext_vector_type(8))) short bf16x8;
typedef __attribute__((ext_vector_type(4))) float f32x4;

__device__ inline unsigned short f2bf(float f) {
    unsigned u = __builtin_bit_cast(unsigned, f);
    unsigned r = (u + 0x7fffu + ((u >> 16) & 1u)) >> 16;
    return (unsigned short)r;
}

// ---------------------------------------------------------------------------
// Kernel 1: build trilinear kernel -> bf16 Kb[cell=125][o=64][c=32]
// ---------------------------------------------------------------------------
__global__ __launch_bounds__(128) void build_k(const float* __restrict__ W,
                                               const float* __restrict__ P,
                                               short* __restrict__ Kb) {
    const int pair = blockIdx.x;      // 0..2047
    const int o = pair >> 5;
    const int c = pair & 31;
    const int cell = threadIdx.x;
    if (cell >= 125) return;
    const int l = cell / 25;
    const int j = (cell / 5) % 5;
    const int i = cell % 5;
    const float fl = (float)l, fj = (float)j, fi = (float)i;
    const int base = (o * IC + c) * KC;
    float acc = 0.f;
    #pragma unroll
    for (int k = 0; k < KC; ++k) {
        const float w  = W[base + k];
        const float p1 = P[0 * OC * IC * KC + base + k] + 2.0f;  // depth
        const float p2 = P[1 * OC * IC * KC + base + k] + 2.0f;  // width
        const float p3 = P[2 * OC * IC * KC + base + k] + 2.0f;  // height
        const float f1 = floorf(p1), r1 = p1 - f1;
        const float f2 = floorf(p2), r2 = p2 - f2;
        const float f3 = floorf(p3), r3 = p3 - f3;
        const float wl = (fl == f1) ? (1.f - r1) : ((fl == f1 + 1.f) ? r1 : 0.f);
        const float wj = (fj == f3) ? (1.f - r3) : ((fj == f3 + 1.f) ? r3 : 0.f);
        const float wi = (fi == f2) ? (1.f - r2) : ((fi == f2 + 1.f) ? r2 : 0.f);
        acc += w * (wl * wj * wi);
    }
    Kb[(cell * OC + o) * IC + c] = (short)f2bf(acc);
}

// ---------------------------------------------------------------------------
// Kernel 2: transpose + zero-pad x -> bf16 x_p[n][z=20][h=36][w=36][slot=4][8c]
// slot s at width w holds channel-group (s ^ (w&3))  (source-side XOR swizzle)
// ---------------------------------------------------------------------------
__global__ __launch_bounds__(128) void xpose(const float* __restrict__ x,
                                             short* __restrict__ xp) {
    const int b = blockIdx.x;          // 0..1439 = n(2) x z(20) x h(36)
    const int n = b / 720;
    const int rem = b - n * 720;
    const int z = rem / 36;
    const int h = rem - z * 36;
    const int zr = z - 2, hr = h - 2;
    short* orow = xp + (size_t)((n * 20 + z) * 36 + h) * (36 * 32);

    if ((unsigned)zr >= 16u || (unsigned)hr >= 32u) {
        for (int idx = threadIdx.x; idx < 144; idx += 128)
            *reinterpret_cast<float4*>(orow + idx * 8) = make_float4(0.f, 0.f, 0.f, 0.f);
        return;
    }

    __shared__ float sR[32][36];
    const float* xb = x + ((size_t)(n * 32) * 16 + zr) * 1024 + hr * 32;
    for (int idx = threadIdx.x; idx < 32 * 36; idx += 128) {
        const int c = idx / 36;
        const int w = idx - c * 36;
        const int wr = w - 2;
        float v = 0.f;
        if ((unsigned)wr < 32u) v = xb[(size_t)c * 16384 + wr];
        sR[c][w] = v;
    }
    __syncthreads();
    for (int idx = threadIdx.x; idx < 144; idx += 128) {
        const int w = idx >> 2;
        const int s = idx & 3;
        const int c0 = (s ^ (w & 3)) * 8;
        bf16x8 pk;
        #pragma unroll
        for (int e = 0; e < 8; ++e) pk[e] = (short)f2bf(sR[c0 + e][w]);
        *reinterpret_cast<bf16x8*>(orow + idx * 8) = pk;
    }
}

// ---------------------------------------------------------------------------
// Kernel 3: implicit-GEMM conv via MFMA 16x16x32 bf16, software-pipelined.
// Block = (n, d, h0=4 rows), 512 thr = 8 waves (2 o-tiles x 4 h-rows).
// 25 (l,j)-rows of 5 cells; per row 10 A-frags (global, L1/L2) + 10 B-frags
// (LDS) double-buffered with prefetch distance 1.
// ---------------------------------------------------------------------------
__global__ __launch_bounds__(512) void conv_mfma(const short* __restrict__ Kb,
                                                 const short* __restrict__ xp,
                                                 const float* __restrict__ bias,
                                                 float* __restrict__ out) {
    // XCD-aware chunked swizzle: 256 blocks, 8 XCDs, 32 per XCD contiguous.
    const int bx = (blockIdx.x & 7) * 32 + (blockIdx.x >> 3);
    const int hb = bx & 7;
    const int d  = (bx >> 3) & 15;
    const int n  = bx >> 7;
    const int h0 = hb * 4;

    __shared__ short sX[5 * 8 * 36 * 32];   // 92160 B

    const int tid = threadIdx.x;

    // ---- stage 92160B via global_load_lds (layout is verbatim-linear) ----
    {
        const short* src = xp + (size_t)((n * 20 + d) * 36 + h0) * 1152;
        #pragma unroll
        for (int k = 0; k < 11; ++k) {
            const int t = k * 512 + tid;
            const int zi = t / 1152;
            const int rm = t - zi * 1152;
            __builtin_amdgcn_global_load_lds(
                (const __attribute__((address_space(1))) unsigned int*)(src + zi * 41472 + rm * 8),
                (__attribute__((address_space(3))) unsigned int*)(sX + t * 8),
                16, 0, 0);
        }
        if (tid < 128) {
            const int t = 11 * 512 + tid;   // 5632..5759, zi=4 always
            const int rm = t - 4 * 1152;
            __builtin_amdgcn_global_load_lds(
                (const __attribute__((address_space(1))) unsigned int*)(src + 4 * 41472 + rm * 8),
                (__attribute__((address_space(3))) unsigned int*)(sX + t * 8),
                16, 0, 0);
        }
    }
    __syncthreads();

    const int wv   = tid >> 6;
    const int lane = tid & 63;
    const int mi   = wv & 1;                // o-tile
    const int rr   = wv >> 1;               // h-row within block
    const int o_base = mi * 32;
    const int col = lane & 15;
    const int cg  = lane >> 4;              // k-block (8 channels)

    const short* pA = Kb + (o_base + col) * 32 + cg * 8;   // advances per row

    // per-lane B byte-index offsets within a zh-row (swizzled), in shorts
    int boff[2][5];
    #pragma unroll
    for (int f = 0; f < 2; ++f)
        #pragma unroll
        for (int i = 0; i < 5; ++i) {
            const int w = col + f * 16 + i;
            boff[f][i] = w * 32 + ((cg ^ (w & 3)) << 3);
        }

    f32x4 acc[2][2] = {{{0.f, 0.f, 0.f, 0.f}, {0.f, 0.f, 0.f, 0.f}},
                       {{0.f, 0.f, 0.f, 0.f}, {0.f, 0.f, 0.f, 0.f}}};

    bf16x8 A0[2][5], B0[2][5], A1[2][5], B1[2][5];

#define LOAD_ROW(Ab, Bb, pa, zhrow)                                          \
    {                                                                        \
        const short* Br_ = sX + (zhrow) * 1152;                              \
        _Pragma("unroll")                                                    \
        for (int i_ = 0; i_ < 5; ++i_) {                                     \
            Ab[0][i_] = *reinterpret_cast<const bf16x8*>((pa) + i_ * 2048);  \
            Ab[1][i_] = *reinterpret_cast<const bf16x8*>((pa) + i_ * 2048 + 512); \
            Bb[0][i_] = *reinterpret_cast<const bf16x8*>(Br_ + boff[0][i_]); \
            Bb[1][i_] = *reinterpret_cast<const bf16x8*>(Br_ + boff[1][i_]); \
        }                                                                    \
    }

#define MFMA_ROW(Ab, Bb)                                                     \
    {                                                                        \
        __builtin_amdgcn_s_setprio(1);                                       \
        _Pragma("unroll")                                                    \
        for (int i_ = 0; i_ < 5; ++i_) {                                     \
            acc[0][0] = __builtin_amdgcn_mfma_f32_16x16x32_bf16(Ab[0][i_], Bb[0][i_], acc[0][0], 0, 0, 0); \
            acc[0][1] = __builtin_amdgcn_mfma_f32_16x16x32_bf16(Ab[0][i_], Bb[1][i_], acc[0][1], 0, 0, 0); \
            acc[1][0] = __builtin_amdgcn_mfma_f32_16x16x32_bf16(Ab[1][i_], Bb[0][i_], acc[1][0], 0, 0, 0); \
            acc[1][1] = __builtin_amdgcn_mfma_f32_16x16x32_bf16(Ab[1][i_], Bb[1][i_], acc[1][1], 0, 0, 0); \
        }                                                                    \
        __builtin_amdgcn_s_setprio(0);                                       \
    }

    int zh = rr;       // zh of the row being loaded next (after prologue)
    int jc = 0;        // j of that row

    LOAD_ROW(A0, B0, pA, zh);          // row 0
    pA += 10240;
    zh += 1; jc = 1;

    #pragma unroll 1
    for (int t = 0; t < 12; ++t) {
        // load row 2t+1 into A1/B1, compute row 2t from A0/B0
        LOAD_ROW(A1, B1, pA, zh);
        pA += 10240;
        zh += 1; if (++jc == 5) { jc = 0; zh += 3; }
        MFMA_ROW(A0, B0);
        // load row 2t+2 into A0/B0, compute row 2t+1 from A1/B1
        LOAD_ROW(A0, B0, pA, zh);
        pA += 10240;
        zh += 1; if (++jc == 5) { jc = 0; zh += 3; }
        MFMA_ROW(A1, B1);
    }
    MFMA_ROW(A0, B0);                  // row 24

#undef LOAD_ROW
#undef MFMA_ROW

    // ---- epilogue: C/D layout col=lane&15 (w), row=cg*4+reg (o) ----
    const int h = h0 + rr;
    #pragma unroll
    for (int mf = 0; mf < 2; ++mf) {
        #pragma unroll
        for (int f = 0; f < 2; ++f) {
            #pragma unroll
            for (int reg = 0; reg < 4; ++reg) {
                const int o = o_base + mf * 16 + cg * 4 + reg;
                const int w = f * 16 + col;
                out[(((size_t)(n * 64 + o) * 16 + d) * 32 + h) * 32 + w] =
                    acc[mf][f][reg] + bias[o];
            }
        }
    }
}

extern "C" void kernel_launch(void* const* d_in, const int* in_sizes, int n_in,
                              void* d_out, int out_size, void* d_ws, size_t ws_size,
                              hipStream_t stream) {
    const float* x    = (const float*)d_in[0];
    const float* W    = (const float*)d_in[1];
    const float* P    = (const float*)d_in[2];
    const float* bias = (const float*)d_in[3];
    float* outp = (float*)d_out;

    short* Kb = (short*)d_ws;                          // 125*64*32*2 = 512000 B
    short* xp = (short*)((char*)d_ws + 524288);        // 2*20*36*36*64 = 3317760 B

    build_k<<<OC * IC, 128, 0, stream>>>(W, P, Kb);
    xpose<<<2 * 20 * 36, 128, 0, stream>>>(x, xp);
    conv_mfma<<<256, 512, 0, stream>>>(Kb, xp, bias, outp);
}